// Round 5
// baseline (233.603 us; speedup 1.0000x reference)
//
#include <hip/hip_runtime.h>

// YOLO loss forward on MI355X.
// input/target: (B=256, C=25, S=64, S=64) fp32, row-major.
// Memory-bound reduction: 209.7 MB -> 1 float.
//
// V6: window-sequential streaming. Cross-round evidence: delivered rate
// tracks the grid's INSTANTANEOUS footprint, not occupancy or per-thread
// load count (V1/V2/V3/V5 whole-buffer scatter = 2.5-2.7 TB/s; V4's
// windowed class loop = 3.87 TB/s; sequential copy = 6.3 TB/s).
// Per-CU in-flight is ~fixed -> throughput = in-flight / latency; lower
// latency via contiguous working windows.
//  - class items mapped to FLAT memory order (img = f/20480): iteration i
//    of the grid-stride loop covers one contiguous ~8.4 MB window of in
//    and tg. Loop shape = V4's (2 items/iter), which the compiler
//    software-pipelines (VGPR 52) unlike straight-line load blocks.
//  - mask precomputed as uchar4 (1 MB, ~4 KB per image window, L2-hot,
//    reused 20x) instead of V4's 4 MB float4 (was 80 MB of stream).
//  - box kernel: V4 shape, separate dispatch (ablation row).

#define COORD 5.0f
#define NOOBJ 0.5f

constexpr int B = 256;
constexpr int C = 25;
constexpr int S = 64;
constexpr int SS = S * S;                    // 4096 spatial positions per image
constexpr int CH_STRIDE4 = SS / 4;           // 1024 float4 per channel plane
constexpr int IMG_STRIDE4 = C * CH_STRIDE4;  // 25600 float4 per image
constexpr int N4 = B * SS / 4;               // 262144 float4-groups (= 2^18)

constexpr int THREADS = 256;
constexpr int CLASS_CH = 20;                              // channels 5..24
constexpr int CLASS_ITEMS = CLASS_CH * N4;                // 5,242,880
constexpr int CLASS_W = CLASS_CH * CH_STRIDE4;            // 20480 class-float4 per image
constexpr int CLASS_BLOCKS = 2048;
constexpr int CLASS_THREADS_TOT = CLASS_BLOCKS * THREADS; // 524,288
constexpr int CLASS_IPT = CLASS_ITEMS / CLASS_THREADS_TOT; // 10 items/thread
constexpr int BOX_BLOCKS = N4 / THREADS;                  // 1024
constexpr int MASK_BYTES = N4 * 4;                        // uchar4 per group, 1 MB

__device__ __forceinline__ float comp(const float4 v, int k) {
    switch (k) {
        case 0: return v.x;
        case 1: return v.y;
        case 2: return v.z;
        default: return v.w;
    }
}

__device__ __forceinline__ void block_reduce_atomic(float acc, float* out) {
    #pragma unroll
    for (int off = 32; off > 0; off >>= 1)
        acc += __shfl_down(acc, off, 64);
    __shared__ float smem[4];
    const int lane = threadIdx.x & 63;
    const int wid = threadIdx.x >> 6;
    if (lane == 0) smem[wid] = acc;
    __syncthreads();
    if (threadIdx.x == 0) {
        atomicAdd(out, smem[0] + smem[1] + smem[2] + smem[3]);
    }
}

__global__ void zero_out_kernel(float* out) { out[0] = 0.0f; }

// uchar4 objectness mask per float4-group: mask[g] = (t4 > 0)
__global__ __launch_bounds__(256) void mask_kernel(
        const float4* __restrict__ tg, uchar4* __restrict__ mask) {
    const int g = blockIdx.x * 256 + threadIdx.x;  // grid = N4/256 = 1024 blocks
    const float4 t4 = tg[(g >> 10) * IMG_STRIDE4 + (g & 1023) + 4 * CH_STRIDE4];
    mask[g] = make_uchar4(t4.x > 0.0f, t4.y > 0.0f, t4.z > 0.0f, t4.w > 0.0f);
}

// ---- class terms: sum m * (p_c - t_c)^2 over channels 5..24 ----
// Items in FLAT memory order: f -> (img = f/CLASS_W, rem = f%CLASS_W),
// addr = img*IMG_STRIDE4 + 5*CH_STRIDE4 + rem. Iteration i covers the
// contiguous window f in [i*2^19, (i+1)*2^19).
__global__ __launch_bounds__(256) void class_kernel(
        const float4* __restrict__ in, const float4* __restrict__ tg,
        const uchar4* __restrict__ mask,  // may be null -> derive from tg
        float* __restrict__ out) {
    const int t = blockIdx.x * THREADS + threadIdx.x;
    float acc = 0.0f;

    #pragma unroll
    for (int i = 0; i < CLASS_IPT; i += 2) {
        const int f0 = t + (i + 0) * CLASS_THREADS_TOT;
        const int f1 = t + (i + 1) * CLASS_THREADS_TOT;
        const int img0 = f0 / CLASS_W;                 // magic-mul division
        const int img1 = f1 / CLASS_W;
        const int rem0 = f0 - img0 * CLASS_W;
        const int rem1 = f1 - img1 * CLASS_W;
        const int a0 = img0 * IMG_STRIDE4 + 5 * CH_STRIDE4 + rem0;
        const int a1 = img1 * IMG_STRIDE4 + 5 * CH_STRIDE4 + rem1;
        const int g0 = (img0 << 10) + (rem0 & 1023);   // mask index
        const int g1 = (img1 << 10) + (rem1 & 1023);

        const float4 pv0 = in[a0];
        const float4 tv0 = tg[a0];
        const float4 pv1 = in[a1];
        const float4 tv1 = tg[a1];
        float m0x, m0y, m0z, m0w, m1x, m1y, m1z, m1w;
        if (mask) {
            const uchar4 mk0 = mask[g0];
            const uchar4 mk1 = mask[g1];
            m0x = mk0.x; m0y = mk0.y; m0z = mk0.z; m0w = mk0.w;
            m1x = mk1.x; m1y = mk1.y; m1z = mk1.z; m1w = mk1.w;
        } else {
            const float4 a = tg[(g0 >> 10) * IMG_STRIDE4 + (g0 & 1023) + 4 * CH_STRIDE4];
            const float4 b = tg[(g1 >> 10) * IMG_STRIDE4 + (g1 & 1023) + 4 * CH_STRIDE4];
            m0x = a.x > 0.0f ? 1.0f : 0.0f; m0y = a.y > 0.0f ? 1.0f : 0.0f;
            m0z = a.z > 0.0f ? 1.0f : 0.0f; m0w = a.w > 0.0f ? 1.0f : 0.0f;
            m1x = b.x > 0.0f ? 1.0f : 0.0f; m1y = b.y > 0.0f ? 1.0f : 0.0f;
            m1z = b.z > 0.0f ? 1.0f : 0.0f; m1w = b.w > 0.0f ? 1.0f : 0.0f;
        }

        float d;
        d = pv0.x - tv0.x; acc = fmaf(m0x * d, d, acc);
        d = pv0.y - tv0.y; acc = fmaf(m0y * d, d, acc);
        d = pv0.z - tv0.z; acc = fmaf(m0z * d, d, acc);
        d = pv0.w - tv0.w; acc = fmaf(m0w * d, d, acc);
        d = pv1.x - tv1.x; acc = fmaf(m1x * d, d, acc);
        d = pv1.y - tv1.y; acc = fmaf(m1y * d, d, acc);
        d = pv1.z - tv1.z; acc = fmaf(m1z * d, d, acc);
        d = pv1.w - tv1.w; acc = fmaf(m1w * d, d, acc);
    }

    block_reduce_atomic(acc, out);
}

// ---- box terms: channels 0..4 (coord + iou + conf + noobj) ----
__global__ __launch_bounds__(256) void box_kernel(
        const float4* __restrict__ in, const float4* __restrict__ tg,
        float* __restrict__ out) {
    const int g = blockIdx.x * THREADS + threadIdx.x;  // < N4
    const int base = (g >> 10) * IMG_STRIDE4 + (g & 1023);

    const float4 p0 = in[base + 0 * CH_STRIDE4];
    const float4 p1 = in[base + 1 * CH_STRIDE4];
    const float4 p2 = in[base + 2 * CH_STRIDE4];
    const float4 p3 = in[base + 3 * CH_STRIDE4];
    const float4 p4 = in[base + 4 * CH_STRIDE4];
    const float4 t0 = tg[base + 0 * CH_STRIDE4];
    const float4 t1 = tg[base + 1 * CH_STRIDE4];
    const float4 t2 = tg[base + 2 * CH_STRIDE4];
    const float4 t3 = tg[base + 3 * CH_STRIDE4];
    const float4 t4 = tg[base + 4 * CH_STRIDE4];

    float acc = 0.0f;
    const float invBlocks = 1.0f / (float)S;
    #pragma unroll
    for (int k = 0; k < 4; ++k) {
        const float px = comp(p0, k), py = comp(p1, k);
        const float pw = comp(p2, k), ph = comp(p3, k);
        const float pc = comp(p4, k);
        const float tx = comp(t0, k), ty = comp(t1, k);
        const float tw = comp(t2, k), th = comp(t3, k);
        const float tc = comp(t4, k);
        const float m = (tc > 0.0f) ? 1.0f : 0.0f;

        // IoU (forward values only)
        const float c1x = px * invBlocks, c1y = py * invBlocks;
        const float c2x = tx * invBlocks, c2y = ty * invBlocks;
        const float x1a = c1x - pw * 0.5f, x2a = c1x + pw * 0.5f;
        const float y1a = c1y - ph * 0.5f, y2a = c1y + ph * 0.5f;
        const float x1b = c2x - tw * 0.5f, x2b = c2x + tw * 0.5f;
        const float y1b = c2y - th * 0.5f, y2b = c2y + th * 0.5f;
        const float dx = fminf(x2a, x2b) - fmaxf(x1a, x1b);
        const float dy = fminf(y2a, y2b) - fmaxf(y1a, y1b);
        const float inter = dx * dy;
        const float uni = pw * ph + tw * th - inter;
        const bool pos = (dx > 0.0f) && (dy > 0.0f);
        const float iou = pos ? (inter / uni) : 0.0f;

        // coord terms
        const float ex = px - tx, ey = py - ty;
        acc += COORD * m * (ex * ex + ey * ey);
        const float sw = sqrtf(pw) - sqrtf(tw);
        const float sh = sqrtf(ph) - sqrtf(th);
        acc += COORD * m * (sw * sw + sh * sh);
        // confidence terms
        const float ec = pc - iou;
        acc += m * ec * ec;
        acc += NOOBJ * (1.0f - m) * (pc * pc);
    }

    block_reduce_atomic(acc, out);
}

extern "C" void kernel_launch(void* const* d_in, const int* in_sizes, int n_in,
                              void* d_out, int out_size, void* d_ws, size_t ws_size,
                              hipStream_t stream) {
    const float4* in = (const float4*)d_in[0];
    const float4* tg = (const float4*)d_in[1];
    float* out = (float*)d_out;

    // d_out is re-poisoned to 0xAA before every timed launch -> zero it first.
    zero_out_kernel<<<1, 1, 0, stream>>>(out);

    uchar4* mask = nullptr;
    if (d_ws != nullptr && ws_size >= (size_t)MASK_BYTES) {
        mask = (uchar4*)d_ws;
        mask_kernel<<<N4 / 256, 256, 0, stream>>>(tg, mask);
    }

    class_kernel<<<CLASS_BLOCKS, THREADS, 0, stream>>>(in, tg, mask, out);
    box_kernel<<<BOX_BLOCKS, THREADS, 0, stream>>>(in, tg, out);
}